// Round 6
// baseline (85.540 us; speedup 1.0000x reference)
//
#include <hip/hip_runtime.h>

#define SPLIT0 513

// cos/sin(-2*pi*j/32), exact constant twiddles for the in-register 32-pt FFTs.
constexpr float W32R[16] = {
    1.0f,          0.980785280f,  0.923879533f,  0.831469612f,
    0.707106781f,  0.555570233f,  0.382683432f,  0.195090322f,
    0.0f,         -0.195090322f, -0.382683432f, -0.555570233f,
   -0.707106781f, -0.831469612f, -0.923879533f, -0.980785280f};
constexpr float W32I[16] = {
    0.0f,         -0.195090322f, -0.382683432f, -0.555570233f,
   -0.707106781f, -0.831469612f, -0.923879533f, -0.980785280f,
   -1.0f,         -0.980785280f, -0.923879533f, -0.831469612f,
   -0.707106781f, -0.555570233f, -0.382683432f, -0.195090322f};
// 5-bit bit-reversal (DIT input permutation).
constexpr int BR5[32] = {0,16,8,24,4,20,12,28,2,18,10,26,6,22,14,30,
                         1,17,9,25,5,21,13,29,3,19,11,27,7,23,15,31};

// In-register 32-pt DIT FFT; expects input in bit-reversed order, outputs
// natural order. All twiddles compile-time constants; fully unrolled.
__device__ __forceinline__ void fft32(float2* z) {
    #pragma unroll
    for (int s = 1; s <= 5; ++s) {
        const int half = 1 << (s - 1);
        const int tstep = 1 << (5 - s);
        #pragma unroll
        for (int g = 0; g < 32; g += (1 << s)) {
            #pragma unroll
            for (int j = 0; j < half; ++j) {
                const int p0 = g + j, p1 = p0 + half;
                const float wr = W32R[j * tstep], wi = W32I[j * tstep];
                float tr = z[p1].x * wr - z[p1].y * wi;
                float ti = z[p1].x * wi + z[p1].y * wr;
                z[p1] = make_float2(z[p0].x - tr, z[p0].y - ti);
                z[p0] = make_float2(z[p0].x + tr, z[p0].y + ti);
            }
        }
    }
}

// Four-step 1024-pt FFT: n = n1 + 32*n2, k = k1 + 32*k2.
// (1) thread (f,n1): A[k1] = FFT32 over n2 of z[n1 + 32*n2]   (in registers)
// (2) B[n1][k1] = A[k1] * W1024^(n1*k1)                        (recurrence)
// (3) LDS transpose (swizzled, conflict-free)                  (ONE barrier)
// (4) thread (f,k1): X[k1+32*k2] = FFT32 over n1 of B[n1][k1]  (in registers)
// (5) untangle two real rows via conjugate-partner wave shuffle; store.
__global__ __launch_bounds__(128, 2) void rfft1024_4step(const float* __restrict__ x,
                                                         float* __restrict__ out,
                                                         int nrows) {
    // 4 FFTs/block, swizzled 32x32 transpose buffer per FFT: 32 KiB total.
    __shared__ float2 T[4 * 32 * 32];

    const int t = threadIdx.x;
    const int f = t >> 5;    // FFT slot in block, 0..3
    const int n1 = t & 31;
    const int P = blockIdx.x * 4 + f;  // complex-pair index (2 real rows)
    const float* __restrict__ r0 = x + (size_t)(2 * P) * 1024;
    const float* __restrict__ r1 = r0 + 1024;

    // ---- stage 1 load: z[i] = x[n1 + 32*br(i)] (+ i*row1), coalesced 128B runs
    float2 z[32];
    #pragma unroll
    for (int i = 0; i < 32; ++i) {
        const int off = n1 + 32 * BR5[i];
        z[i] = make_float2(r0[off], r1[off]);
    }
    fft32(z);  // z[k1] = A[n1][k1], natural k1

    // ---- twiddle by W1024^(n1*k1) and write transposed into LDS.
    // Swizzled addr: T[f][n1][k1] at f*1024 + n1*32 + ((k1+n1)&31)
    {
        float2* __restrict__ Tf = &T[f * 1024 + n1 * 32];
        const float ph = (float)n1 * (-1.0f / 1024.0f);  // revolutions
        const float wbr = __builtin_amdgcn_cosf(ph);
        const float wbi = __builtin_amdgcn_sinf(ph);
        Tf[n1 & 31] = z[0];  // k1 = 0, w = 1
        float wr = wbr, wi = wbi;
        #pragma unroll
        for (int k1 = 1; k1 < 32; ++k1) {
            Tf[(k1 + n1) & 31] =
                make_float2(z[k1].x * wr - z[k1].y * wi,
                            z[k1].x * wi + z[k1].y * wr);
            const float nwr = wr * wbr - wi * wbi;
            wi = wr * wbi + wi * wbr;
            wr = nwr;
        }
    }
    __syncthreads();  // the ONLY barrier

    // ---- stage 2: thread handles k1 = n1; read B[n1][k1] over bit-reversed n1.
    const int k1 = n1;
    {
        const float2* __restrict__ Tb = &T[f * 1024];
        #pragma unroll
        for (int i = 0; i < 32; ++i) {
            const int nn = BR5[i];
            z[i] = Tb[nn * 32 + ((k1 + nn) & 31)];
        }
    }
    fft32(z);  // z[k2] = X[k1 + 32*k2], natural k2

    // ---- untangle + store. Z[1024-k] lives in partner lane (32-k1)&31 of the
    // same 32-lane group, register index 31-k2 (k1!=0); k1==0 uses own regs.
    const int partner = (t & 32) | ((32 - k1) & 31);
    const size_t row0 = (size_t)(2 * P);
    float* __restrict__ outr = out + row0 * SPLIT0;
    float* __restrict__ outi = out + (size_t)nrows * SPLIT0 + row0 * SPLIT0;

    #pragma unroll
    for (int k2 = 0; k2 <= 16; ++k2) {
        float zmr = __shfl(z[31 - k2].x, partner, 64);
        float zmi = __shfl(z[31 - k2].y, partner, 64);
        if (k1 == 0) {  // own register: Z[(1024-32*k2) mod 1024] = z[(32-k2)&31]
            zmr = z[(32 - k2) & 31].x;
            zmi = z[(32 - k2) & 31].y;
        }
        const float zr = z[k2].x, zi = z[k2].y;
        const float X0r = 0.5f * (zr + zmr), X0i = 0.5f * (zi - zmi);
        const float X1r = 0.5f * (zi + zmi), X1i = 0.5f * (zmr - zr);
        const int k = k1 + 32 * k2;
        if (k <= 512) {  // k2<16: all lanes; k2==16: only k1==0 (Nyquist)
            outr[k]          = X0r;
            outi[k]          = X0i;
            outr[SPLIT0 + k] = X1r;  // row0+1
            outi[SPLIT0 + k] = X1i;
        }
    }
}

extern "C" void kernel_launch(void* const* d_in, const int* in_sizes, int n_in,
                              void* d_out, int out_size, void* d_ws, size_t ws_size,
                              hipStream_t stream) {
    const float* x = (const float*)d_in[0];
    float* out = (float*)d_out;
    const int nrows = in_sizes[0] / 1024;  // 8192
    const int npairs = nrows / 2;          // 4096
    rfft1024_4step<<<npairs / 4, 128, 0, stream>>>(x, out, nrows);
}